// Round 10
// baseline (163.099 us; speedup 1.0000x reference)
//
#include <hip/hip_runtime.h>
#include <hip/hip_bf16.h>
#include <math.h>

#define LEN_IN   16660
#define D_MODEL  256
#define N_HEADS  8
#define HEAD_DIM 32

typedef __attribute__((ext_vector_type(8))) short short8v;
typedef __attribute__((ext_vector_type(4))) float f32x4;
typedef _Float16 f16x2 __attribute__((ext_vector_type(2)));
typedef _Float16 f16x8 __attribute__((ext_vector_type(8)));

__device__ __forceinline__ unsigned short f2h(float f) {
  union { unsigned short u; _Float16 h; } c;
  c.h = (_Float16)f;
  return c.u;
}
__device__ __forceinline__ float h2f(unsigned short u) {
  union { unsigned short u; _Float16 h; } c;
  c.u = u;
  return (float)c.h;
}
__device__ __forceinline__ f16x2 u2h(unsigned u) {
  union { unsigned u; f16x2 h; } c;
  c.u = u;
  return c.h;
}

// ---------------------------------------------------------------------------
// Prep: transpose + f16-cast 5 weight matrices. Bt[n][k] = f16(W[k][n]).
// ---------------------------------------------------------------------------
__global__ __launch_bounds__(256) void prep_B(
    const float* __restrict__ Wq, const float* __restrict__ Wk,
    const float* __restrict__ Wv, const float* __restrict__ Woff,
    const float* __restrict__ Wo,
    unsigned short* __restrict__ Btq, unsigned short* __restrict__ Btk,
    unsigned short* __restrict__ Btv, unsigned short* __restrict__ Btoff,
    unsigned short* __restrict__ Bto) {
  __shared__ float tile[64][65];
  int b = blockIdx.x;
  int mat = b >> 4, t = b & 15;
  int ti = t >> 2, tj = t & 3;
  const float* W = (mat == 0) ? Wq : (mat == 1) ? Wk : (mat == 2) ? Wv
                 : (mat == 3) ? Woff : Wo;
  unsigned short* Bt = (mat == 0) ? Btq : (mat == 1) ? Btk : (mat == 2) ? Btv
                     : (mat == 3) ? Btoff : Bto;
  int tid = threadIdx.x;
  #pragma unroll
  for (int i = 0; i < 16; i++) {
    int idx = tid + i * 256;
    int kr = idx >> 6, nc = idx & 63;
    tile[kr][nc] = W[(size_t)(ti * 64 + kr) * 256 + tj * 64 + nc];
  }
  __syncthreads();
  #pragma unroll
  for (int i = 0; i < 16; i++) {
    int idx = tid + i * 256;
    int nr = idx >> 6, kc = idx & 63;
    Bt[(size_t)(tj * 64 + nr) * 256 + ti * 64 + kc] = f2h(tile[kc][nr]);
  }
}

// ---------------------------------------------------------------------------
// Fused q-proj (z=0) + kv-proj (z=1). A f32 -> f16 LDS; f16 MFMA.
// z=0: qp (f16) = query@Wq + bq.  z=1: k,v planes (f16) = inp@{Wk,Wv} + b.
// ---------------------------------------------------------------------------
__global__ __launch_bounds__(256) void gemm_qkv(
    const float* __restrict__ query, const float* __restrict__ inp,
    const unsigned short* __restrict__ Btq,
    const unsigned short* __restrict__ Btk,
    const unsigned short* __restrict__ Btv,
    const float* __restrict__ bq, const float* __restrict__ bk,
    const float* __restrict__ bv,
    unsigned short* __restrict__ qp_out,
    unsigned short* __restrict__ k_out, unsigned short* __restrict__ v_out,
    int M) {
  const int P = 40;
  __shared__ short As[64 * P], B1[64 * P], B2[64 * P];
  bool isq = (blockIdx.z == 0);
  const float* A = isq ? query : inp;
  int tid = threadIdx.x;
  int m0 = blockIdx.x * 64, n0 = blockIdx.y * 64;
  int w = tid >> 6, l = tid & 63;
  int r = l & 15, g = l >> 4;
  int mi = (w >> 1) * 32, ni = (w & 1) * 32;
  int sm = tid >> 2, sp = tid & 3;

  f32x4 acc1[2][2], acc2[2][2];
  #pragma unroll
  for (int a = 0; a < 2; a++)
    #pragma unroll
    for (int b = 0; b < 2; b++) {
      acc1[a][b] = (f32x4){0.f, 0.f, 0.f, 0.f};
      acc2[a][b] = (f32x4){0.f, 0.f, 0.f, 0.f};
    }

  for (int k0 = 0; k0 < 256; k0 += 32) {
    int gm = m0 + sm;
    float f[8];
    if (gm < M) {
      const float* src = A + (size_t)gm * 256 + k0 + sp * 8;
      float4 u0 = *(const float4*)src;
      float4 u1 = *(const float4*)(src + 4);
      f[0] = u0.x; f[1] = u0.y; f[2] = u0.z; f[3] = u0.w;
      f[4] = u1.x; f[5] = u1.y; f[6] = u1.z; f[7] = u1.w;
    } else {
      #pragma unroll
      for (int j = 0; j < 8; j++) f[j] = 0.f;
    }
    f16x8 hv;
    #pragma unroll
    for (int j = 0; j < 8; j++) hv[j] = (_Float16)f[j];
    *(f16x8*)&As[sm * P + sp * 8] = hv;
    if (isq) {
      *(short8v*)&B1[sm * P + sp * 8] =
          *(const short8v*)&Btq[(size_t)(n0 + sm) * 256 + k0 + sp * 8];
    } else {
      *(short8v*)&B1[sm * P + sp * 8] =
          *(const short8v*)&Btk[(size_t)(n0 + sm) * 256 + k0 + sp * 8];
      *(short8v*)&B2[sm * P + sp * 8] =
          *(const short8v*)&Btv[(size_t)(n0 + sm) * 256 + k0 + sp * 8];
    }
    __syncthreads();

    f16x8 af[2], b1f[2], b2f[2];
    #pragma unroll
    for (int a = 0; a < 2; a++)
      af[a] = *(f16x8*)&As[(mi + a * 16 + r) * P + g * 8];
    #pragma unroll
    for (int b = 0; b < 2; b++)
      b1f[b] = *(f16x8*)&B1[(ni + b * 16 + r) * P + g * 8];
    if (!isq) {
      #pragma unroll
      for (int b = 0; b < 2; b++)
        b2f[b] = *(f16x8*)&B2[(ni + b * 16 + r) * P + g * 8];
    }
    #pragma unroll
    for (int a = 0; a < 2; a++)
      #pragma unroll
      for (int b = 0; b < 2; b++) {
        acc1[a][b] = __builtin_amdgcn_mfma_f32_16x16x32_f16(af[a], b1f[b], acc1[a][b], 0, 0, 0);
        if (!isq)
          acc2[a][b] = __builtin_amdgcn_mfma_f32_16x16x32_f16(af[a], b2f[b], acc2[a][b], 0, 0, 0);
      }
    __syncthreads();
  }

  #pragma unroll
  for (int a = 0; a < 2; a++)
    #pragma unroll
    for (int b = 0; b < 2; b++) {
      int col = n0 + ni + b * 16 + r;
      if (isq) {
        float bc = bq[col];
        #pragma unroll
        for (int i = 0; i < 4; i++) {
          int row = m0 + mi + a * 16 + g * 4 + i;
          if (row < M) qp_out[(size_t)row * 256 + col] = f2h(acc1[a][b][i] + bc);
        }
      } else {
        float bkc = bk[col], bvc = bv[col];
        #pragma unroll
        for (int i = 0; i < 4; i++) {
          int row = m0 + mi + a * 16 + g * 4 + i;
          if (row < M) {
            k_out[(size_t)row * 256 + col] = f2h(acc1[a][b][i] + bkc);
            v_out[(size_t)row * 256 + col] = f2h(acc2[a][b][i] + bvc);
          }
        }
      }
    }
}

// ---------------------------------------------------------------------------
// f16-A GEMM (A already f16 in memory): C = A @ Bt^T + bias.
// OUT_F16: store f16, else f32.
// ---------------------------------------------------------------------------
template <bool OUT_F16>
__global__ __launch_bounds__(256) void gemm_a16(
    const unsigned short* __restrict__ A,   // f16 bits (M,256)
    const unsigned short* __restrict__ Bt,  // f16 bits (256,256) [n][k]
    const float* __restrict__ bias, void* __restrict__ Cout, int M) {
  const int P = 40;
  __shared__ short As[64 * P], Bs[64 * P];
  int tid = threadIdx.x;
  int m0 = blockIdx.x * 64, n0 = blockIdx.y * 64;
  int w = tid >> 6, l = tid & 63;
  int r = l & 15, g = l >> 4;
  int mi = (w >> 1) * 32, ni = (w & 1) * 32;
  int sm = tid >> 2, sp = tid & 3;

  f32x4 acc[2][2];
  #pragma unroll
  for (int a = 0; a < 2; a++)
    #pragma unroll
    for (int b = 0; b < 2; b++) acc[a][b] = (f32x4){0.f, 0.f, 0.f, 0.f};

  for (int k0 = 0; k0 < 256; k0 += 32) {
    int gm = m0 + sm;
    short8v av = {0, 0, 0, 0, 0, 0, 0, 0};
    if (gm < M)
      av = *(const short8v*)&A[(size_t)gm * 256 + k0 + sp * 8];
    *(short8v*)&As[sm * P + sp * 8] = av;
    *(short8v*)&Bs[sm * P + sp * 8] =
        *(const short8v*)&Bt[(size_t)(n0 + sm) * 256 + k0 + sp * 8];
    __syncthreads();

    f16x8 af[2], bf[2];
    #pragma unroll
    for (int a = 0; a < 2; a++)
      af[a] = *(f16x8*)&As[(mi + a * 16 + r) * P + g * 8];
    #pragma unroll
    for (int b = 0; b < 2; b++)
      bf[b] = *(f16x8*)&Bs[(ni + b * 16 + r) * P + g * 8];
    #pragma unroll
    for (int a = 0; a < 2; a++)
      #pragma unroll
      for (int b = 0; b < 2; b++)
        acc[a][b] = __builtin_amdgcn_mfma_f32_16x16x32_f16(af[a], bf[b], acc[a][b], 0, 0, 0);
    __syncthreads();
  }

  #pragma unroll
  for (int a = 0; a < 2; a++)
    #pragma unroll
    for (int b = 0; b < 2; b++) {
      int col = n0 + ni + b * 16 + r;
      float bc = bias[col];
      #pragma unroll
      for (int i = 0; i < 4; i++) {
        int row = m0 + mi + a * 16 + g * 4 + i;
        if (row < M) {
          float v = acc[a][b][i] + bc;
          if (OUT_F16)
            ((unsigned short*)Cout)[(size_t)row * 256 + col] = f2h(v);
          else
            ((float*)Cout)[(size_t)row * 256 + col] = v;
        }
      }
    }
}

// ---------------------------------------------------------------------------
// Sampling + attention v4: TWO (query,head) pairs per wave.
// lane = (qin = lane>>5) x (pt = (lane&31)>>1, chunk = lane&1 of 16 chan).
// Split k/v f16 planes; v_dot2_f32_f16 for q.k; packed f16 FMA taps.
// ---------------------------------------------------------------------------
__global__ __launch_bounds__(256) void sample_attn(
    const unsigned short* __restrict__ qp,     // f16 (LEN,256)
    const unsigned short* __restrict__ offs,   // f16 (LEN,256)
    const float* __restrict__ rp,              // (LEN,8)
    const unsigned short* __restrict__ kplane, // f16 (LEN,256)
    const unsigned short* __restrict__ vplane, // f16 (LEN,256)
    unsigned short* __restrict__ attn_out) {   // f16 (LEN,256)
  __shared__ float lbuf[4][2][16];
  __shared__ float ebuf[4][2][16];
  __shared__ float vbuf[4][2][16][34];  // +2 pad

  int tid = threadIdx.x;
  int wslot = tid >> 6;
  int lane = tid & 63;
  int qin = lane >> 5;
  int l5 = lane & 31;
  int pt = l5 >> 1;
  int cp = lane & 1;
  int widp = blockIdx.x * 8 + wslot * 2 + qin;
  int q = widp >> 3;
  int h = widp & 7;

  float offv = h2f(offs[(size_t)q * 256 + h * 32 + l5]);
  float rpv = (l5 < 8) ? rp[(size_t)q * 8 + l5] : 0.f;

  int l = pt >> 2, pp = pt & 3;
  int W = 112 >> l;
  int start = (int)((50176u - (50176u >> (2 * l))) / 3u);  // 0,12544,15680,16464

  float off_x = __shfl(offv, l * 8 + pp * 2 + 0, 32);
  float off_y = __shfl(offv, l * 8 + pp * 2 + 1, 32);
  float rp_x = __shfl(rpv, l * 2 + 0, 32);
  float rp_y = __shfl(rpv, l * 2 + 1, 32);

  float x = rp_x * (float)W + off_x - 0.5f;
  float y = rp_y * (float)W + off_y - 0.5f;
  float x0f = floorf(x), y0f = floorf(y);
  float lx = x - x0f, ly = y - y0f;
  int x0 = (int)x0f, y0 = (int)y0f;
  float wx0 = 1.f - lx, wy0 = 1.f - ly;
  float tw[4] = {wy0 * wx0, wy0 * lx, ly * wx0, ly * lx};

  int coff = h * 32 + cp * 16;  // channel offset (shorts)

  f16x2 kacc[8], vacc[8];
  #pragma unroll
  for (int j = 0; j < 8; j++) {
    kacc[j] = (f16x2){(_Float16)0.f, (_Float16)0.f};
    vacc[j] = (f16x2){(_Float16)0.f, (_Float16)0.f};
  }

  #pragma unroll
  for (int tap = 0; tap < 4; tap++) {
    int yy = y0 + (tap >> 1), xx = x0 + (tap & 1);
    bool valid = ((unsigned)xx < (unsigned)W) & ((unsigned)yy < (unsigned)W);
    float wgt = valid ? tw[tap] : 0.f;
    int pix = valid ? (start + yy * W + xx) : start;
    size_t base = (size_t)pix * 256 + coff;
    uint4 k0 = *(const uint4*)(kplane + base);
    uint4 k1 = *(const uint4*)(kplane + base + 8);
    uint4 v0 = *(const uint4*)(vplane + base);
    uint4 v1 = *(const uint4*)(vplane + base + 8);
    _Float16 wh = (_Float16)wgt;
    f16x2 w2 = {wh, wh};
    kacc[0] += w2 * u2h(k0.x); kacc[1] += w2 * u2h(k0.y);
    kacc[2] += w2 * u2h(k0.z); kacc[3] += w2 * u2h(k0.w);
    kacc[4] += w2 * u2h(k1.x); kacc[5] += w2 * u2h(k1.y);
    kacc[6] += w2 * u2h(k1.z); kacc[7] += w2 * u2h(k1.w);
    vacc[0] += w2 * u2h(v0.x); vacc[1] += w2 * u2h(v0.y);
    vacc[2] += w2 * u2h(v0.z); vacc[3] += w2 * u2h(v0.w);
    vacc[4] += w2 * u2h(v1.x); vacc[5] += w2 * u2h(v1.y);
    vacc[6] += w2 * u2h(v1.z); vacc[7] += w2 * u2h(v1.w);
  }

  // q . k over this lane's 16 channels via v_dot2_f32_f16
  const uint4* qsrc = (const uint4*)(qp + (size_t)q * 256 + coff);
  uint4 qa = qsrc[0], qb = qsrc[1];
  float dot = 0.f;
  dot = __builtin_amdgcn_fdot2(u2h(qa.x), kacc[0], dot, false);
  dot = __builtin_amdgcn_fdot2(u2h(qa.y), kacc[1], dot, false);
  dot = __builtin_amdgcn_fdot2(u2h(qa.z), kacc[2], dot, false);
  dot = __builtin_amdgcn_fdot2(u2h(qa.w), kacc[3], dot, false);
  dot = __builtin_amdgcn_fdot2(u2h(qb.x), kacc[4], dot, false);
  dot = __builtin_amdgcn_fdot2(u2h(qb.y), kacc[5], dot, false);
  dot = __builtin_amdgcn_fdot2(u2h(qb.z), kacc[6], dot, false);
  dot = __builtin_amdgcn_fdot2(u2h(qb.w), kacc[7], dot, false);
  dot += __shfl_xor(dot, 1, 32);
  if (cp == 0) lbuf[wslot][qin][pt] = dot * 0.17677669529663687f;

  // v -> f32 into LDS
  float4 w0 = {(float)vacc[0][0], (float)vacc[0][1], (float)vacc[1][0], (float)vacc[1][1]};
  float4 w1 = {(float)vacc[2][0], (float)vacc[2][1], (float)vacc[3][0], (float)vacc[3][1]};
  float4 w2_ = {(float)vacc[4][0], (float)vacc[4][1], (float)vacc[5][0], (float)vacc[5][1]};
  float4 w3 = {(float)vacc[6][0], (float)vacc[6][1], (float)vacc[7][0], (float)vacc[7][1]};
  float* vdst = &vbuf[wslot][qin][pt][cp * 16];
  *(float4*)(vdst + 0) = w0;
  *(float4*)(vdst + 4) = w1;
  *(float4*)(vdst + 8) = w2_;
  *(float4*)(vdst + 12) = w3;
  __syncthreads();

  // softmax over 16 points (per query half; masks < 16 stay in-group)
  float lg = lbuf[wslot][qin][lane & 15];
  float m = lg;
  m = fmaxf(m, __shfl_xor(m, 1, 32));
  m = fmaxf(m, __shfl_xor(m, 2, 32));
  m = fmaxf(m, __shfl_xor(m, 4, 32));
  m = fmaxf(m, __shfl_xor(m, 8, 32));
  float e = __expf(lg - m);
  float s = e;
  s += __shfl_xor(s, 1, 32);
  s += __shfl_xor(s, 2, 32);
  s += __shfl_xor(s, 4, 32);
  s += __shfl_xor(s, 8, 32);
  if ((lane & 16) == 0) ebuf[wslot][qin][lane & 15] = e;
  float inv = 1.f / s;
  __syncthreads();

  // output: all 64 lanes; lane = (qin, channel lane&31)
  int c = lane & 31;
  float o = 0.f;
  #pragma unroll
  for (int p = 0; p < 16; p++)
    o += ebuf[wslot][qin][p] * vbuf[wslot][qin][p][c];
  attn_out[(size_t)q * 256 + h * 32 + c] = f2h(o * inv);
}

extern "C" void kernel_launch(void* const* d_in, const int* in_sizes, int n_in,
                              void* d_out, int out_size, void* d_ws, size_t ws_size,
                              hipStream_t stream) {
  const float* query = (const float*)d_in[0];
  const float* rp    = (const float*)d_in[1];
  const float* inp   = (const float*)d_in[2];
  const float* W_q   = (const float*)d_in[5];
  const float* b_q   = (const float*)d_in[6];
  const float* W_k   = (const float*)d_in[7];
  const float* b_k   = (const float*)d_in[8];
  const float* W_v   = (const float*)d_in[9];
  const float* b_v   = (const float*)d_in[10];
  const float* W_o   = (const float*)d_in[11];
  const float* b_o   = (const float*)d_in[12];
  const float* W_off = (const float*)d_in[13];
  const float* b_off = (const float*)d_in[14];
  float* out = (float*)d_out;

  const size_t nelem = (size_t)LEN_IN * D_MODEL;  // 4,264,960
  unsigned short* qp    = (unsigned short*)d_ws;
  unsigned short* offsb = qp + nelem;
  unsigned short* attn  = offsb + nelem;
  unsigned short* kpl   = attn + nelem;
  unsigned short* vpl   = kpl + nelem;
  unsigned short* Btq   = vpl + nelem;
  unsigned short* Btk   = Btq + 256 * 256;
  unsigned short* Btv   = Btk + 256 * 256;
  unsigned short* Btoff = Btv + 256 * 256;
  unsigned short* Bto   = Btoff + 256 * 256;

  dim3 blk(256);
  dim3 ggrid((LEN_IN + 63) / 64, D_MODEL / 64);         // (261, 4)
  dim3 ggrid2((LEN_IN + 63) / 64, D_MODEL / 64, 2);     // q + kv fused

  prep_B<<<80, blk, 0, stream>>>(W_q, W_k, W_v, W_off, W_o,
                                 Btq, Btk, Btv, Btoff, Bto);
  gemm_qkv<<<ggrid2, blk, 0, stream>>>(query, inp, Btq, Btk, Btv,
                                       b_q, b_k, b_v, qp, kpl, vpl, LEN_IN);
  gemm_a16<true><<<ggrid, blk, 0, stream>>>(qp, Btoff, b_off, offsb, LEN_IN);

  sample_attn<<<LEN_IN, blk, 0, stream>>>(qp, offsb, rp, kpl, vpl, attn);

  gemm_a16<false><<<ggrid, blk, 0, stream>>>(attn, Bto, b_o, out, LEN_IN);
}

// Round 11
// 145.765 us; speedup vs baseline: 1.1189x; 1.1189x over previous
//
#include <hip/hip_runtime.h>
#include <hip/hip_bf16.h>
#include <math.h>

#define LEN_IN   16660
#define D_MODEL  256
#define N_HEADS  8

typedef __attribute__((ext_vector_type(8))) short short8v;
typedef __attribute__((ext_vector_type(4))) float f32x4;
typedef _Float16 f16x2 __attribute__((ext_vector_type(2)));
typedef _Float16 f16x8 __attribute__((ext_vector_type(8)));

__device__ __forceinline__ unsigned short f2h(float f) {
  union { unsigned short u; _Float16 h; } c;
  c.h = (_Float16)f;
  return c.u;
}
__device__ __forceinline__ float h2f(unsigned short u) {
  union { unsigned short u; _Float16 h; } c;
  c.u = u;
  return (float)c.h;
}
__device__ __forceinline__ f16x2 u2h(unsigned u) {
  union { unsigned u; f16x2 h; } c;
  c.u = u;
  return c.h;
}

// ---------------------------------------------------------------------------
// Prep: transpose + f16-cast 5 weight matrices. Bt[n][k] = f16(W[k][n]).
// ---------------------------------------------------------------------------
__global__ __launch_bounds__(256) void prep_B(
    const float* __restrict__ Wq, const float* __restrict__ Wk,
    const float* __restrict__ Wv, const float* __restrict__ Woff,
    const float* __restrict__ Wo,
    unsigned short* __restrict__ Btq, unsigned short* __restrict__ Btk,
    unsigned short* __restrict__ Btv, unsigned short* __restrict__ Btoff,
    unsigned short* __restrict__ Bto) {
  __shared__ float tile[64][65];
  int b = blockIdx.x;
  int mat = b >> 4, t = b & 15;
  int ti = t >> 2, tj = t & 3;
  const float* W = (mat == 0) ? Wq : (mat == 1) ? Wk : (mat == 2) ? Wv
                 : (mat == 3) ? Woff : Wo;
  unsigned short* Bt = (mat == 0) ? Btq : (mat == 1) ? Btk : (mat == 2) ? Btv
                     : (mat == 3) ? Btoff : Bto;
  int tid = threadIdx.x;
  #pragma unroll
  for (int i = 0; i < 16; i++) {
    int idx = tid + i * 256;
    int kr = idx >> 6, nc = idx & 63;
    tile[kr][nc] = W[(size_t)(ti * 64 + kr) * 256 + tj * 64 + nc];
  }
  __syncthreads();
  #pragma unroll
  for (int i = 0; i < 16; i++) {
    int idx = tid + i * 256;
    int nr = idx >> 6, kc = idx & 63;
    Bt[(size_t)(tj * 64 + nr) * 256 + ti * 64 + kc] = f2h(tile[kc][nr]);
  }
}

// bqo[j] = sum_i bq[i] * Woff[i][j] + boff[j]   (coalesced per-iteration rows)
__global__ void bqo_kernel(const float* __restrict__ bq,
                           const float* __restrict__ Woff,
                           const float* __restrict__ boff,
                           float* __restrict__ bqo) {
  int j = threadIdx.x;
  float s = boff[j];
  for (int i = 0; i < 256; i++) s += bq[i] * Woff[(size_t)i * 256 + j];
  bqo[j] = s;
}

// ---------------------------------------------------------------------------
// Wqo = Wq @ Woff, stored transposed f16: Btqo[n][m] = f16(Wqo[m][n]).
// A = Wq f32; B = Btoff (f16, [n][k]). grid (4,4), M=256.
// ---------------------------------------------------------------------------
__global__ __launch_bounds__(256) void gemm_wqo(
    const float* __restrict__ Wq, const unsigned short* __restrict__ Btoff,
    unsigned short* __restrict__ Btqo) {
  const int P = 40;
  __shared__ short As[64 * P], Bs[64 * P];
  int tid = threadIdx.x;
  int m0 = blockIdx.x * 64, n0 = blockIdx.y * 64;
  int w = tid >> 6, l = tid & 63;
  int r = l & 15, g = l >> 4;
  int mi = (w >> 1) * 32, ni = (w & 1) * 32;
  int sm = tid >> 2, sp = tid & 3;

  f32x4 acc[2][2];
  #pragma unroll
  for (int a = 0; a < 2; a++)
    #pragma unroll
    for (int b = 0; b < 2; b++) acc[a][b] = (f32x4){0.f, 0.f, 0.f, 0.f};

  for (int k0 = 0; k0 < 256; k0 += 32) {
    const float* src = Wq + (size_t)(m0 + sm) * 256 + k0 + sp * 8;
    float4 u0 = *(const float4*)src;
    float4 u1 = *(const float4*)(src + 4);
    f16x8 hv = {(_Float16)u0.x, (_Float16)u0.y, (_Float16)u0.z, (_Float16)u0.w,
                (_Float16)u1.x, (_Float16)u1.y, (_Float16)u1.z, (_Float16)u1.w};
    *(f16x8*)&As[sm * P + sp * 8] = hv;
    *(short8v*)&Bs[sm * P + sp * 8] =
        *(const short8v*)&Btoff[(size_t)(n0 + sm) * 256 + k0 + sp * 8];
    __syncthreads();
    f16x8 af[2], bf[2];
    #pragma unroll
    for (int a = 0; a < 2; a++)
      af[a] = *(f16x8*)&As[(mi + a * 16 + r) * P + g * 8];
    #pragma unroll
    for (int b = 0; b < 2; b++)
      bf[b] = *(f16x8*)&Bs[(ni + b * 16 + r) * P + g * 8];
    #pragma unroll
    for (int a = 0; a < 2; a++)
      #pragma unroll
      for (int b = 0; b < 2; b++)
        acc[a][b] = __builtin_amdgcn_mfma_f32_16x16x32_f16(af[a], bf[b], acc[a][b], 0, 0, 0);
    __syncthreads();
  }
  #pragma unroll
  for (int a = 0; a < 2; a++)
    #pragma unroll
    for (int b = 0; b < 2; b++) {
      int col = n0 + ni + b * 16 + r;
      #pragma unroll
      for (int i = 0; i < 4; i++) {
        int row = m0 + mi + a * 16 + g * 4 + i;
        Btqo[(size_t)col * 256 + row] = f2h(acc[a][b][i]);  // transposed store
      }
    }
}

// ---------------------------------------------------------------------------
// Fused projections, z-indexed: z=0 qp(f16)=query@Wq+bq ; z=1 packed kv
// (uint={k|v<<16}) = inp@{Wk,Wv}+b ; z=2 offs(f16)=query@Wqo+bqo.
// ---------------------------------------------------------------------------
__global__ __launch_bounds__(256) void gemm_qkv(
    const float* __restrict__ query, const float* __restrict__ inp,
    const unsigned short* __restrict__ Btq,
    const unsigned short* __restrict__ Btk,
    const unsigned short* __restrict__ Btv,
    const unsigned short* __restrict__ Btqo,
    const float* __restrict__ bq, const float* __restrict__ bk,
    const float* __restrict__ bv, const float* __restrict__ bqo,
    unsigned short* __restrict__ qp_out, unsigned* __restrict__ kv_out,
    unsigned short* __restrict__ offs_out, int M) {
  const int P = 40;
  __shared__ short As[64 * P], B1[64 * P], B2[64 * P];
  int z = blockIdx.z;
  const float* A = (z == 1) ? inp : query;
  const unsigned short* Bt1 = (z == 0) ? Btq : (z == 1) ? Btk : Btqo;
  int tid = threadIdx.x;
  int m0 = blockIdx.x * 64, n0 = blockIdx.y * 64;
  int w = tid >> 6, l = tid & 63;
  int r = l & 15, g = l >> 4;
  int mi = (w >> 1) * 32, ni = (w & 1) * 32;
  int sm = tid >> 2, sp = tid & 3;

  f32x4 acc1[2][2], acc2[2][2];
  #pragma unroll
  for (int a = 0; a < 2; a++)
    #pragma unroll
    for (int b = 0; b < 2; b++) {
      acc1[a][b] = (f32x4){0.f, 0.f, 0.f, 0.f};
      acc2[a][b] = (f32x4){0.f, 0.f, 0.f, 0.f};
    }

  for (int k0 = 0; k0 < 256; k0 += 32) {
    int gm = m0 + sm;
    float f[8];
    if (gm < M) {
      const float* src = A + (size_t)gm * 256 + k0 + sp * 8;
      float4 u0 = *(const float4*)src;
      float4 u1 = *(const float4*)(src + 4);
      f[0] = u0.x; f[1] = u0.y; f[2] = u0.z; f[3] = u0.w;
      f[4] = u1.x; f[5] = u1.y; f[6] = u1.z; f[7] = u1.w;
    } else {
      #pragma unroll
      for (int j = 0; j < 8; j++) f[j] = 0.f;
    }
    f16x8 hv;
    #pragma unroll
    for (int j = 0; j < 8; j++) hv[j] = (_Float16)f[j];
    *(f16x8*)&As[sm * P + sp * 8] = hv;
    *(short8v*)&B1[sm * P + sp * 8] =
        *(const short8v*)&Bt1[(size_t)(n0 + sm) * 256 + k0 + sp * 8];
    if (z == 1)
      *(short8v*)&B2[sm * P + sp * 8] =
          *(const short8v*)&Btv[(size_t)(n0 + sm) * 256 + k0 + sp * 8];
    __syncthreads();

    f16x8 af[2], b1f[2], b2f[2];
    #pragma unroll
    for (int a = 0; a < 2; a++)
      af[a] = *(f16x8*)&As[(mi + a * 16 + r) * P + g * 8];
    #pragma unroll
    for (int b = 0; b < 2; b++)
      b1f[b] = *(f16x8*)&B1[(ni + b * 16 + r) * P + g * 8];
    if (z == 1) {
      #pragma unroll
      for (int b = 0; b < 2; b++)
        b2f[b] = *(f16x8*)&B2[(ni + b * 16 + r) * P + g * 8];
    }
    #pragma unroll
    for (int a = 0; a < 2; a++)
      #pragma unroll
      for (int b = 0; b < 2; b++) {
        acc1[a][b] = __builtin_amdgcn_mfma_f32_16x16x32_f16(af[a], b1f[b], acc1[a][b], 0, 0, 0);
        if (z == 1)
          acc2[a][b] = __builtin_amdgcn_mfma_f32_16x16x32_f16(af[a], b2f[b], acc2[a][b], 0, 0, 0);
      }
    __syncthreads();
  }

  #pragma unroll
  for (int a = 0; a < 2; a++)
    #pragma unroll
    for (int b = 0; b < 2; b++) {
      int col = n0 + ni + b * 16 + r;
      if (z == 0) {
        float bc = bq[col];
        #pragma unroll
        for (int i = 0; i < 4; i++) {
          int row = m0 + mi + a * 16 + g * 4 + i;
          if (row < M) qp_out[(size_t)row * 256 + col] = f2h(acc1[a][b][i] + bc);
        }
      } else if (z == 1) {
        float bkc = bk[col], bvc = bv[col];
        #pragma unroll
        for (int i = 0; i < 4; i++) {
          int row = m0 + mi + a * 16 + g * 4 + i;
          if (row < M) {
            unsigned kh = f2h(acc1[a][b][i] + bkc);
            unsigned vh = f2h(acc2[a][b][i] + bvc);
            kv_out[(size_t)row * 256 + col] = kh | (vh << 16);
          }
        }
      } else {
        float bc = bqo[col];
        #pragma unroll
        for (int i = 0; i < 4; i++) {
          int row = m0 + mi + a * 16 + g * 4 + i;
          if (row < M) offs_out[(size_t)row * 256 + col] = f2h(acc1[a][b][i] + bc);
        }
      }
    }
}

// ---------------------------------------------------------------------------
// Output projection: A f16 (attn), f32 out.
// ---------------------------------------------------------------------------
__global__ __launch_bounds__(256) void gemm_out(
    const unsigned short* __restrict__ A,
    const unsigned short* __restrict__ Bt,
    const float* __restrict__ bias, float* __restrict__ C, int M) {
  const int P = 40;
  __shared__ short As[64 * P], Bs[64 * P];
  int tid = threadIdx.x;
  int m0 = blockIdx.x * 64, n0 = blockIdx.y * 64;
  int w = tid >> 6, l = tid & 63;
  int r = l & 15, g = l >> 4;
  int mi = (w >> 1) * 32, ni = (w & 1) * 32;
  int sm = tid >> 2, sp = tid & 3;

  f32x4 acc[2][2];
  #pragma unroll
  for (int a = 0; a < 2; a++)
    #pragma unroll
    for (int b = 0; b < 2; b++) acc[a][b] = (f32x4){0.f, 0.f, 0.f, 0.f};

  for (int k0 = 0; k0 < 256; k0 += 32) {
    int gm = m0 + sm;
    short8v av = {0, 0, 0, 0, 0, 0, 0, 0};
    if (gm < M)
      av = *(const short8v*)&A[(size_t)gm * 256 + k0 + sp * 8];
    *(short8v*)&As[sm * P + sp * 8] = av;
    *(short8v*)&Bs[sm * P + sp * 8] =
        *(const short8v*)&Bt[(size_t)(n0 + sm) * 256 + k0 + sp * 8];
    __syncthreads();
    f16x8 af[2], bf[2];
    #pragma unroll
    for (int a = 0; a < 2; a++)
      af[a] = *(f16x8*)&As[(mi + a * 16 + r) * P + g * 8];
    #pragma unroll
    for (int b = 0; b < 2; b++)
      bf[b] = *(f16x8*)&Bs[(ni + b * 16 + r) * P + g * 8];
    #pragma unroll
    for (int a = 0; a < 2; a++)
      #pragma unroll
      for (int b = 0; b < 2; b++)
        acc[a][b] = __builtin_amdgcn_mfma_f32_16x16x32_f16(af[a], bf[b], acc[a][b], 0, 0, 0);
    __syncthreads();
  }
  #pragma unroll
  for (int a = 0; a < 2; a++)
    #pragma unroll
    for (int b = 0; b < 2; b++) {
      int col = n0 + ni + b * 16 + r;
      float bc = bias[col];
      #pragma unroll
      for (int i = 0; i < 4; i++) {
        int row = m0 + mi + a * 16 + g * 4 + i;
        if (row < M) C[(size_t)row * 256 + col] = acc[a][b][i] + bc;
      }
    }
}

// ---------------------------------------------------------------------------
// Sampling + attention v5: one wave per (query, head); ZERO LDS, no barriers.
// lane = pt(lane>>2) x chunk(lane&3, 8 channels). Interleaved packed f16 kv.
// Softmax + output reduction entirely via shfl_xor (strides 4,8,16,32).
// ---------------------------------------------------------------------------
__global__ __launch_bounds__(256) void sample_attn(
    const unsigned short* __restrict__ qp,    // f16 (LEN,256)
    const unsigned short* __restrict__ offs,  // f16 (LEN,256)
    const float* __restrict__ rp,             // f32 (LEN,8)
    const unsigned* __restrict__ kv,          // packed f16 {k|v<<16}
    unsigned short* __restrict__ attn_out) {  // f16 (LEN,256)
  int tid = threadIdx.x;
  int wslot = tid >> 6;
  int lane = tid & 63;
  int wid = blockIdx.x * 4 + wslot;
  int q = wid >> 3;
  int h = wid & 7;

  int pt = lane >> 2;        // point 0..15
  int c8 = (lane & 3) * 8;   // channel chunk base
  int l5 = lane & 31;

  float offv = h2f(offs[(size_t)q * 256 + h * 32 + l5]);
  float rpv = (l5 < 8) ? rp[(size_t)q * 8 + l5] : 0.f;

  int l = pt >> 2, pp = pt & 3;
  int W = 112 >> l;
  int start = (int)((50176u - (50176u >> (2 * l))) / 3u);  // 0,12544,15680,16464

  float off_x = __shfl(offv, l * 8 + pp * 2 + 0, 32);
  float off_y = __shfl(offv, l * 8 + pp * 2 + 1, 32);
  float rp_x = __shfl(rpv, l * 2 + 0, 32);
  float rp_y = __shfl(rpv, l * 2 + 1, 32);

  float x = rp_x * (float)W + off_x - 0.5f;
  float y = rp_y * (float)W + off_y - 0.5f;
  float x0f = floorf(x), y0f = floorf(y);
  float lx = x - x0f, ly = y - y0f;
  int x0 = (int)x0f, y0 = (int)y0f;
  float wx0 = 1.f - lx, wy0 = 1.f - ly;
  float tw[4] = {wy0 * wx0, wy0 * lx, ly * wx0, ly * lx};

  int hoff = h * 32 + c8;

  f16x2 acc[8];
  #pragma unroll
  for (int j = 0; j < 8; j++) acc[j] = (f16x2){(_Float16)0.f, (_Float16)0.f};

  #pragma unroll
  for (int tap = 0; tap < 4; tap++) {
    int yy = y0 + (tap >> 1), xx = x0 + (tap & 1);
    bool valid = ((unsigned)xx < (unsigned)W) & ((unsigned)yy < (unsigned)W);
    float wgt = valid ? tw[tap] : 0.f;
    int pix = valid ? (start + yy * W + xx) : start;
    const unsigned* p = kv + (size_t)pix * 256 + hoff;
    uint4 u0 = *(const uint4*)p;
    uint4 u1 = *(const uint4*)(p + 4);
    _Float16 wh = (_Float16)wgt;
    f16x2 w2 = {wh, wh};
    acc[0] += w2 * u2h(u0.x);
    acc[1] += w2 * u2h(u0.y);
    acc[2] += w2 * u2h(u0.z);
    acc[3] += w2 * u2h(u0.w);
    acc[4] += w2 * u2h(u1.x);
    acc[5] += w2 * u2h(u1.y);
    acc[6] += w2 * u2h(u1.z);
    acc[7] += w2 * u2h(u1.w);
  }

  // q . k via fdot2 on paired k's (low halves of acc)
  uint4 qa = *(const uint4*)(qp + (size_t)q * 256 + hoff);
  float dot = 0.f;
  f16x2 kp;
  kp[0] = acc[0][0]; kp[1] = acc[1][0];
  dot = __builtin_amdgcn_fdot2(u2h(qa.x), kp, dot, false);
  kp[0] = acc[2][0]; kp[1] = acc[3][0];
  dot = __builtin_amdgcn_fdot2(u2h(qa.y), kp, dot, false);
  kp[0] = acc[4][0]; kp[1] = acc[5][0];
  dot = __builtin_amdgcn_fdot2(u2h(qa.z), kp, dot, false);
  kp[0] = acc[6][0]; kp[1] = acc[7][0];
  dot = __builtin_amdgcn_fdot2(u2h(qa.w), kp, dot, false);
  dot += __shfl_xor(dot, 1, 64);
  dot += __shfl_xor(dot, 2, 64);
  float logit = dot * 0.17677669529663687f;

  // softmax across the 16 point-lanes (strides 4..32 preserve chunk index)
  float m = logit;
  m = fmaxf(m, __shfl_xor(m, 4, 64));
  m = fmaxf(m, __shfl_xor(m, 8, 64));
  m = fmaxf(m, __shfl_xor(m, 16, 64));
  m = fmaxf(m, __shfl_xor(m, 32, 64));
  float e = __expf(logit - m);
  float ssum = e;
  ssum += __shfl_xor(ssum, 4, 64);
  ssum += __shfl_xor(ssum, 8, 64);
  ssum += __shfl_xor(ssum, 16, 64);
  ssum += __shfl_xor(ssum, 32, 64);

  // output: scale v (high halves) by e, reduce across point-lanes in f32
  float o[8];
  #pragma unroll
  for (int j = 0; j < 8; j++) o[j] = (float)acc[j][1] * e;
  #pragma unroll
  for (int s = 4; s <= 32; s <<= 1) {
    #pragma unroll
    for (int j = 0; j < 8; j++) o[j] += __shfl_xor(o[j], s, 64);
  }

  if (pt == 0) {  // lanes 0..3 hold the full sums for their chunk
    float inv = 1.f / ssum;
    uint4 st;
    st.x = (unsigned)f2h(o[0] * inv) | ((unsigned)f2h(o[1] * inv) << 16);
    st.y = (unsigned)f2h(o[2] * inv) | ((unsigned)f2h(o[3] * inv) << 16);
    st.z = (unsigned)f2h(o[4] * inv) | ((unsigned)f2h(o[5] * inv) << 16);
    st.w = (unsigned)f2h(o[6] * inv) | ((unsigned)f2h(o[7] * inv) << 16);
    *(uint4*)(attn_out + (size_t)q * 256 + hoff) = st;
  }
}

extern "C" void kernel_launch(void* const* d_in, const int* in_sizes, int n_in,
                              void* d_out, int out_size, void* d_ws, size_t ws_size,
                              hipStream_t stream) {
  const float* query = (const float*)d_in[0];
  const float* rp    = (const float*)d_in[1];
  const float* inp   = (const float*)d_in[2];
  const float* W_q   = (const float*)d_in[5];
  const float* b_q   = (const float*)d_in[6];
  const float* W_k   = (const float*)d_in[7];
  const float* b_k   = (const float*)d_in[8];
  const float* W_v   = (const float*)d_in[9];
  const float* b_v   = (const float*)d_in[10];
  const float* W_o   = (const float*)d_in[11];
  const float* b_o   = (const float*)d_in[12];
  const float* W_off = (const float*)d_in[13];
  const float* b_off = (const float*)d_in[14];
  float* out = (float*)d_out;

  const size_t nelem = (size_t)LEN_IN * D_MODEL;  // 4,264,960
  unsigned short* qp    = (unsigned short*)d_ws;
  unsigned short* offsb = qp + nelem;
  unsigned short* attn  = offsb + nelem;
  unsigned* kvp = (unsigned*)(attn + nelem);
  unsigned short* Btq   = (unsigned short*)(kvp + nelem);
  unsigned short* Btk   = Btq + 256 * 256;
  unsigned short* Btv   = Btk + 256 * 256;
  unsigned short* Btoff = Btv + 256 * 256;
  unsigned short* Bto   = Btoff + 256 * 256;
  unsigned short* Btqo  = Bto + 256 * 256;
  float* bqo = (float*)(Btqo + 256 * 256);

  dim3 blk(256);
  dim3 ggrid((LEN_IN + 63) / 64, D_MODEL / 64);      // (261, 4)
  dim3 ggrid3((LEN_IN + 63) / 64, D_MODEL / 64, 3);  // q + kv + off fused

  prep_B<<<80, blk, 0, stream>>>(W_q, W_k, W_v, W_off, W_o,
                                 Btq, Btk, Btv, Btoff, Bto);
  gemm_wqo<<<dim3(4, 4), blk, 0, stream>>>(W_q, Btoff, Btqo);
  bqo_kernel<<<1, blk, 0, stream>>>(b_q, W_off, b_off, bqo);

  gemm_qkv<<<ggrid3, blk, 0, stream>>>(query, inp, Btq, Btk, Btv, Btqo,
                                       b_q, b_k, b_v, bqo,
                                       qp, kvp, offsb, LEN_IN);

  int n_blocks = LEN_IN * N_HEADS / 4;  // 33320
  sample_attn<<<n_blocks, blk, 0, stream>>>(qp, offsb, rp, kvp, attn);

  gemm_out<<<ggrid, blk, 0, stream>>>(attn, Bto, b_o, out, LEN_IN);
}

// Round 12
// 130.178 us; speedup vs baseline: 1.2529x; 1.1197x over previous
//
#include <hip/hip_runtime.h>
#include <hip/hip_bf16.h>
#include <math.h>

#define LEN_IN   16660
#define D_MODEL  256
#define N_HEADS  8

typedef __attribute__((ext_vector_type(8))) short short8v;
typedef __attribute__((ext_vector_type(4))) float f32x4;
typedef _Float16 f16x2 __attribute__((ext_vector_type(2)));
typedef _Float16 f16x8 __attribute__((ext_vector_type(8)));

__device__ __forceinline__ unsigned short f2h(float f) {
  union { unsigned short u; _Float16 h; } c;
  c.h = (_Float16)f;
  return c.u;
}
__device__ __forceinline__ float h2f(unsigned short u) {
  union { unsigned short u; _Float16 h; } c;
  c.u = u;
  return (float)c.h;
}
__device__ __forceinline__ f16x2 u2h(unsigned u) {
  union { unsigned u; f16x2 h; } c;
  c.u = u;
  return c.h;
}

// ---------------------------------------------------------------------------
// Prep: blocks 0..79 transpose + f16-cast 5 weight matrices (Bt[n][k]);
// block 80 computes bqo = b_q @ W_off + b_off.
// ---------------------------------------------------------------------------
__global__ __launch_bounds__(256) void prep_B(
    const float* __restrict__ Wq, const float* __restrict__ Wk,
    const float* __restrict__ Wv, const float* __restrict__ Woff,
    const float* __restrict__ Wo,
    const float* __restrict__ bq, const float* __restrict__ boff,
    unsigned short* __restrict__ Btq, unsigned short* __restrict__ Btk,
    unsigned short* __restrict__ Btv, unsigned short* __restrict__ Btoff,
    unsigned short* __restrict__ Bto, float* __restrict__ bqo) {
  int b = blockIdx.x;
  int tid = threadIdx.x;
  if (b == 80) {
    float s = boff[tid];
    for (int i = 0; i < 256; i++) s += bq[i] * Woff[(size_t)i * 256 + tid];
    bqo[tid] = s;
    return;
  }
  __shared__ float tile[64][65];
  int mat = b >> 4, t = b & 15;
  int ti = t >> 2, tj = t & 3;
  const float* W = (mat == 0) ? Wq : (mat == 1) ? Wk : (mat == 2) ? Wv
                 : (mat == 3) ? Woff : Wo;
  unsigned short* Bt = (mat == 0) ? Btq : (mat == 1) ? Btk : (mat == 2) ? Btv
                     : (mat == 3) ? Btoff : Bto;
  #pragma unroll
  for (int i = 0; i < 16; i++) {
    int idx = tid + i * 256;
    int kr = idx >> 6, nc = idx & 63;
    tile[kr][nc] = W[(size_t)(ti * 64 + kr) * 256 + tj * 64 + nc];
  }
  __syncthreads();
  #pragma unroll
  for (int i = 0; i < 16; i++) {
    int idx = tid + i * 256;
    int nr = idx >> 6, kc = idx & 63;
    Bt[(size_t)(tj * 64 + nr) * 256 + ti * 64 + kc] = f2h(tile[kc][nr]);
  }
}

// ---------------------------------------------------------------------------
// Wqo = Wq @ Woff, stored transposed f16: Btqo[n][m] = f16(Wqo[m][n]).
// ---------------------------------------------------------------------------
__global__ __launch_bounds__(256) void gemm_wqo(
    const float* __restrict__ Wq, const unsigned short* __restrict__ Btoff,
    unsigned short* __restrict__ Btqo) {
  const int P = 40;
  __shared__ short As[64 * P], Bs[64 * P];
  int tid = threadIdx.x;
  int m0 = blockIdx.x * 64, n0 = blockIdx.y * 64;
  int w = tid >> 6, l = tid & 63;
  int r = l & 15, g = l >> 4;
  int mi = (w >> 1) * 32, ni = (w & 1) * 32;
  int sm = tid >> 2, sp = tid & 3;

  f32x4 acc[2][2];
  #pragma unroll
  for (int a = 0; a < 2; a++)
    #pragma unroll
    for (int b = 0; b < 2; b++) acc[a][b] = (f32x4){0.f, 0.f, 0.f, 0.f};

  for (int k0 = 0; k0 < 256; k0 += 32) {
    const float* src = Wq + (size_t)(m0 + sm) * 256 + k0 + sp * 8;
    float4 u0 = *(const float4*)src;
    float4 u1 = *(const float4*)(src + 4);
    f16x8 hv = {(_Float16)u0.x, (_Float16)u0.y, (_Float16)u0.z, (_Float16)u0.w,
                (_Float16)u1.x, (_Float16)u1.y, (_Float16)u1.z, (_Float16)u1.w};
    *(f16x8*)&As[sm * P + sp * 8] = hv;
    *(short8v*)&Bs[sm * P + sp * 8] =
        *(const short8v*)&Btoff[(size_t)(n0 + sm) * 256 + k0 + sp * 8];
    __syncthreads();
    f16x8 af[2], bf[2];
    #pragma unroll
    for (int a = 0; a < 2; a++)
      af[a] = *(f16x8*)&As[(mi + a * 16 + r) * P + g * 8];
    #pragma unroll
    for (int b = 0; b < 2; b++)
      bf[b] = *(f16x8*)&Bs[(ni + b * 16 + r) * P + g * 8];
    #pragma unroll
    for (int a = 0; a < 2; a++)
      #pragma unroll
      for (int b = 0; b < 2; b++)
        acc[a][b] = __builtin_amdgcn_mfma_f32_16x16x32_f16(af[a], bf[b], acc[a][b], 0, 0, 0);
    __syncthreads();
  }
  #pragma unroll
  for (int a = 0; a < 2; a++)
    #pragma unroll
    for (int b = 0; b < 2; b++) {
      int col = n0 + ni + b * 16 + r;
      #pragma unroll
      for (int i = 0; i < 4; i++) {
        int row = m0 + mi + a * 16 + g * 4 + i;
        Btqo[(size_t)col * 256 + row] = f2h(acc[a][b][i]);  // transposed store
      }
    }
}

// ---------------------------------------------------------------------------
// Fused projections, z-indexed, BK=64 (4 K-iters, 8 barriers/block):
// z=0 qp(f16)=query@Wq+bq ; z=1 HEAD-MAJOR packed kv = inp@{Wk,Wv}+b ;
// z=2 offs(f16)=query@Wqo+bqo.
// ---------------------------------------------------------------------------
__global__ __launch_bounds__(256) void gemm_qkv(
    const float* __restrict__ query, const float* __restrict__ inp,
    const unsigned short* __restrict__ Btq,
    const unsigned short* __restrict__ Btk,
    const unsigned short* __restrict__ Btv,
    const unsigned short* __restrict__ Btqo,
    const float* __restrict__ bq, const float* __restrict__ bk,
    const float* __restrict__ bv, const float* __restrict__ bqo,
    unsigned short* __restrict__ qp_out, unsigned* __restrict__ kv_out,
    unsigned short* __restrict__ offs_out, int M) {
  const int P = 72;  // pitch in shorts for 64-wide f16 rows (144B)
  __shared__ short As[64 * P], B1[64 * P], B2[64 * P];
  int z = blockIdx.z;
  const float* A = (z == 1) ? inp : query;
  const unsigned short* Bt1 = (z == 0) ? Btq : (z == 1) ? Btk : Btqo;
  int tid = threadIdx.x;
  int m0 = blockIdx.x * 64, n0 = blockIdx.y * 64;
  int w = tid >> 6, l = tid & 63;
  int r = l & 15, g = l >> 4;
  int mi = (w >> 1) * 32, ni = (w & 1) * 32;
  int srow = tid >> 2, sch = (tid & 3) * 16;

  f32x4 acc1[2][2], acc2[2][2];
  #pragma unroll
  for (int a = 0; a < 2; a++)
    #pragma unroll
    for (int b = 0; b < 2; b++) {
      acc1[a][b] = (f32x4){0.f, 0.f, 0.f, 0.f};
      acc2[a][b] = (f32x4){0.f, 0.f, 0.f, 0.f};
    }

  for (int k0 = 0; k0 < 256; k0 += 64) {
    int gm = m0 + srow;
    f16x8 h0, h1;
    if (gm < M) {
      const float* src = A + (size_t)gm * 256 + k0 + sch;
      float4 u0 = *(const float4*)src;
      float4 u1 = *(const float4*)(src + 4);
      float4 u2 = *(const float4*)(src + 8);
      float4 u3 = *(const float4*)(src + 12);
      h0 = (f16x8){(_Float16)u0.x, (_Float16)u0.y, (_Float16)u0.z, (_Float16)u0.w,
                   (_Float16)u1.x, (_Float16)u1.y, (_Float16)u1.z, (_Float16)u1.w};
      h1 = (f16x8){(_Float16)u2.x, (_Float16)u2.y, (_Float16)u2.z, (_Float16)u2.w,
                   (_Float16)u3.x, (_Float16)u3.y, (_Float16)u3.z, (_Float16)u3.w};
    } else {
      h0 = (f16x8){0, 0, 0, 0, 0, 0, 0, 0};
      h1 = h0;
    }
    *(f16x8*)&As[srow * P + sch] = h0;
    *(f16x8*)&As[srow * P + sch + 8] = h1;
    {
      const unsigned short* bsrc = Bt1 + (size_t)(n0 + srow) * 256 + k0 + sch;
      *(short8v*)&B1[srow * P + sch] = *(const short8v*)bsrc;
      *(short8v*)&B1[srow * P + sch + 8] = *(const short8v*)(bsrc + 8);
    }
    if (z == 1) {
      const unsigned short* bsrc = Btv + (size_t)(n0 + srow) * 256 + k0 + sch;
      *(short8v*)&B2[srow * P + sch] = *(const short8v*)bsrc;
      *(short8v*)&B2[srow * P + sch + 8] = *(const short8v*)(bsrc + 8);
    }
    __syncthreads();

    f16x8 af[2][2], b1f[2][2], b2f[2][2];
    #pragma unroll
    for (int a = 0; a < 2; a++)
      #pragma unroll
      for (int ks = 0; ks < 2; ks++)
        af[a][ks] = *(f16x8*)&As[(mi + a * 16 + r) * P + ks * 32 + g * 8];
    #pragma unroll
    for (int b = 0; b < 2; b++)
      #pragma unroll
      for (int ks = 0; ks < 2; ks++)
        b1f[b][ks] = *(f16x8*)&B1[(ni + b * 16 + r) * P + ks * 32 + g * 8];
    if (z == 1) {
      #pragma unroll
      for (int b = 0; b < 2; b++)
        #pragma unroll
        for (int ks = 0; ks < 2; ks++)
          b2f[b][ks] = *(f16x8*)&B2[(ni + b * 16 + r) * P + ks * 32 + g * 8];
    }
    #pragma unroll
    for (int a = 0; a < 2; a++)
      #pragma unroll
      for (int b = 0; b < 2; b++)
        #pragma unroll
        for (int ks = 0; ks < 2; ks++) {
          acc1[a][b] = __builtin_amdgcn_mfma_f32_16x16x32_f16(af[a][ks], b1f[b][ks], acc1[a][b], 0, 0, 0);
          if (z == 1)
            acc2[a][b] = __builtin_amdgcn_mfma_f32_16x16x32_f16(af[a][ks], b2f[b][ks], acc2[a][b], 0, 0, 0);
        }
    __syncthreads();
  }

  #pragma unroll
  for (int a = 0; a < 2; a++)
    #pragma unroll
    for (int b = 0; b < 2; b++) {
      int col = n0 + ni + b * 16 + r;
      if (z == 0) {
        float bc = bq[col];
        #pragma unroll
        for (int i = 0; i < 4; i++) {
          int row = m0 + mi + a * 16 + g * 4 + i;
          if (row < M) qp_out[(size_t)row * 256 + col] = f2h(acc1[a][b][i] + bc);
        }
      } else if (z == 1) {
        float bkc = bk[col], bvc = bv[col];
        int hh = col >> 5, cc = col & 31;
        #pragma unroll
        for (int i = 0; i < 4; i++) {
          int row = m0 + mi + a * 16 + g * 4 + i;
          if (row < M) {
            unsigned kh = f2h(acc1[a][b][i] + bkc);
            unsigned vh = f2h(acc2[a][b][i] + bvc);
            kv_out[((size_t)hh * LEN_IN + row) * 32 + cc] = kh | (vh << 16);
          }
        }
      } else {
        float bc = bqo[col];
        #pragma unroll
        for (int i = 0; i < 4; i++) {
          int row = m0 + mi + a * 16 + g * 4 + i;
          if (row < M) offs_out[(size_t)row * 256 + col] = f2h(acc1[a][b][i] + bc);
        }
      }
    }
}

// ---------------------------------------------------------------------------
// Output projection: A f16 (attn), f32 out, BK=64.
// ---------------------------------------------------------------------------
__global__ __launch_bounds__(256) void gemm_out(
    const unsigned short* __restrict__ A,
    const unsigned short* __restrict__ Bt,
    const float* __restrict__ bias, float* __restrict__ C, int M) {
  const int P = 72;
  __shared__ short As[64 * P], Bs[64 * P];
  int tid = threadIdx.x;
  int m0 = blockIdx.x * 64, n0 = blockIdx.y * 64;
  int w = tid >> 6, l = tid & 63;
  int r = l & 15, g = l >> 4;
  int mi = (w >> 1) * 32, ni = (w & 1) * 32;
  int srow = tid >> 2, sch = (tid & 3) * 16;

  f32x4 acc[2][2];
  #pragma unroll
  for (int a = 0; a < 2; a++)
    #pragma unroll
    for (int b = 0; b < 2; b++) acc[a][b] = (f32x4){0.f, 0.f, 0.f, 0.f};

  for (int k0 = 0; k0 < 256; k0 += 64) {
    int gm = m0 + srow;
    short8v a0 = {0, 0, 0, 0, 0, 0, 0, 0}, a1 = a0;
    if (gm < M) {
      const unsigned short* src = A + (size_t)gm * 256 + k0 + sch;
      a0 = *(const short8v*)src;
      a1 = *(const short8v*)(src + 8);
    }
    *(short8v*)&As[srow * P + sch] = a0;
    *(short8v*)&As[srow * P + sch + 8] = a1;
    const unsigned short* bsrc = Bt + (size_t)(n0 + srow) * 256 + k0 + sch;
    *(short8v*)&Bs[srow * P + sch] = *(const short8v*)bsrc;
    *(short8v*)&Bs[srow * P + sch + 8] = *(const short8v*)(bsrc + 8);
    __syncthreads();

    f16x8 af[2][2], bf[2][2];
    #pragma unroll
    for (int a = 0; a < 2; a++)
      #pragma unroll
      for (int ks = 0; ks < 2; ks++)
        af[a][ks] = *(f16x8*)&As[(mi + a * 16 + r) * P + ks * 32 + g * 8];
    #pragma unroll
    for (int b = 0; b < 2; b++)
      #pragma unroll
      for (int ks = 0; ks < 2; ks++)
        bf[b][ks] = *(f16x8*)&Bs[(ni + b * 16 + r) * P + ks * 32 + g * 8];
    #pragma unroll
    for (int a = 0; a < 2; a++)
      #pragma unroll
      for (int b = 0; b < 2; b++)
        #pragma unroll
        for (int ks = 0; ks < 2; ks++)
          acc[a][b] = __builtin_amdgcn_mfma_f32_16x16x32_f16(af[a][ks], bf[b][ks], acc[a][b], 0, 0, 0);
    __syncthreads();
  }
  #pragma unroll
  for (int a = 0; a < 2; a++)
    #pragma unroll
    for (int b = 0; b < 2; b++) {
      int col = n0 + ni + b * 16 + r;
      float bc = bias[col];
      #pragma unroll
      for (int i = 0; i < 4; i++) {
        int row = m0 + mi + a * 16 + g * 4 + i;
        if (row < M) C[(size_t)row * 256 + col] = acc[a][b][i] + bc;
      }
    }
}

// ---------------------------------------------------------------------------
// Sampling + attention v6: R9 structure (1 (q,h)/wave, LDS softmax/output)
// + HEAD-MAJOR packed kv (pixel stride 128B) + fdot2 + f16 qp/offs/attn.
// ---------------------------------------------------------------------------
__global__ __launch_bounds__(256) void sample_attn(
    const unsigned short* __restrict__ qp,    // f16 (LEN,256)
    const unsigned short* __restrict__ offs,  // f16 (LEN,256)
    const float* __restrict__ rp,             // f32 (LEN,8)
    const unsigned* __restrict__ kv,          // packed f16 {k|v<<16}, [h][pix][32]
    unsigned short* __restrict__ attn_out) {  // f16 (LEN,256)
  __shared__ float lbuf[4][16];
  __shared__ float ebuf[4][16];
  __shared__ float vbuf[4][16][36];

  int tid = threadIdx.x;
  int wslot = tid >> 6;
  int lane = tid & 63;
  int wid = blockIdx.x * 4 + wslot;
  int q = wid >> 3;
  int h = wid & 7;

  int pt = lane >> 2;        // point 0..15
  int c8 = (lane & 3) * 8;   // channel chunk base
  int l5 = lane & 31;

  float offv = h2f(offs[(size_t)q * 256 + h * 32 + l5]);
  float rpv = (l5 < 8) ? rp[(size_t)q * 8 + l5] : 0.f;

  int l = pt >> 2, pp = pt & 3;
  int W = 112 >> l;
  int start = (int)((50176u - (50176u >> (2 * l))) / 3u);  // 0,12544,15680,16464

  float off_x = __shfl(offv, l * 8 + pp * 2 + 0, 32);
  float off_y = __shfl(offv, l * 8 + pp * 2 + 1, 32);
  float rp_x = __shfl(rpv, l * 2 + 0, 32);
  float rp_y = __shfl(rpv, l * 2 + 1, 32);

  float x = rp_x * (float)W + off_x - 0.5f;
  float y = rp_y * (float)W + off_y - 0.5f;
  float x0f = floorf(x), y0f = floorf(y);
  float lx = x - x0f, ly = y - y0f;
  int x0 = (int)x0f, y0 = (int)y0f;
  float wx0 = 1.f - lx, wy0 = 1.f - ly;
  float tw[4] = {wy0 * wx0, wy0 * lx, ly * wx0, ly * lx};

  const unsigned* kvh = kv + (size_t)h * LEN_IN * 32 + c8;

  f16x2 acc[8];
  #pragma unroll
  for (int j = 0; j < 8; j++) acc[j] = (f16x2){(_Float16)0.f, (_Float16)0.f};

  #pragma unroll
  for (int tap = 0; tap < 4; tap++) {
    int yy = y0 + (tap >> 1), xx = x0 + (tap & 1);
    bool valid = ((unsigned)xx < (unsigned)W) & ((unsigned)yy < (unsigned)W);
    float wgt = valid ? tw[tap] : 0.f;
    int pix = valid ? (start + yy * W + xx) : start;
    const unsigned* p = kvh + (size_t)pix * 32;
    uint4 u0 = *(const uint4*)p;
    uint4 u1 = *(const uint4*)(p + 4);
    _Float16 wh = (_Float16)wgt;
    f16x2 w2 = {wh, wh};
    acc[0] += w2 * u2h(u0.x);
    acc[1] += w2 * u2h(u0.y);
    acc[2] += w2 * u2h(u0.z);
    acc[3] += w2 * u2h(u0.w);
    acc[4] += w2 * u2h(u1.x);
    acc[5] += w2 * u2h(u1.y);
    acc[6] += w2 * u2h(u1.z);
    acc[7] += w2 * u2h(u1.w);
  }

  // q . k via fdot2 on paired k's (low halves of acc)
  uint4 qa = *(const uint4*)(qp + (size_t)q * 256 + h * 32 + c8);
  float dot = 0.f;
  f16x2 kp;
  kp[0] = acc[0][0]; kp[1] = acc[1][0];
  dot = __builtin_amdgcn_fdot2(u2h(qa.x), kp, dot, false);
  kp[0] = acc[2][0]; kp[1] = acc[3][0];
  dot = __builtin_amdgcn_fdot2(u2h(qa.y), kp, dot, false);
  kp[0] = acc[4][0]; kp[1] = acc[5][0];
  dot = __builtin_amdgcn_fdot2(u2h(qa.z), kp, dot, false);
  kp[0] = acc[6][0]; kp[1] = acc[7][0];
  dot = __builtin_amdgcn_fdot2(u2h(qa.w), kp, dot, false);
  dot += __shfl_xor(dot, 1, 64);
  dot += __shfl_xor(dot, 2, 64);
  if ((lane & 3) == 0) lbuf[wslot][pt] = dot * 0.17677669529663687f;

  // v (high halves) to f32, into LDS
  float4 v0 = {(float)acc[0][1], (float)acc[1][1], (float)acc[2][1], (float)acc[3][1]};
  float4 v1 = {(float)acc[4][1], (float)acc[5][1], (float)acc[6][1], (float)acc[7][1]};
  *(float4*)&vbuf[wslot][pt][c8] = v0;
  *(float4*)&vbuf[wslot][pt][c8 + 4] = v1;
  __syncthreads();

  // softmax over 16 points (redundant per 16-lane group, 1 exp per lane)
  float lg = lbuf[wslot][lane & 15];
  float m = lg;
  m = fmaxf(m, __shfl_xor(m, 1, 64));
  m = fmaxf(m, __shfl_xor(m, 2, 64));
  m = fmaxf(m, __shfl_xor(m, 4, 64));
  m = fmaxf(m, __shfl_xor(m, 8, 64));
  float e = __expf(lg - m);
  float s = e;
  s += __shfl_xor(s, 1, 64);
  s += __shfl_xor(s, 2, 64);
  s += __shfl_xor(s, 4, 64);
  s += __shfl_xor(s, 8, 64);
  if (lane < 16) ebuf[wslot][lane] = e;
  float inv = 1.f / s;
  __syncthreads();

  if (lane < 32) {
    float o = 0.f;
    #pragma unroll
    for (int p = 0; p < 16; p++) o += ebuf[wslot][p] * vbuf[wslot][p][lane];
    attn_out[(size_t)q * 256 + h * 32 + lane] = f2h(o * inv);
  }
}

extern "C" void kernel_launch(void* const* d_in, const int* in_sizes, int n_in,
                              void* d_out, int out_size, void* d_ws, size_t ws_size,
                              hipStream_t stream) {
  const float* query = (const float*)d_in[0];
  const float* rp    = (const float*)d_in[1];
  const float* inp   = (const float*)d_in[2];
  const float* W_q   = (const float*)d_in[5];
  const float* b_q   = (const float*)d_in[6];
  const float* W_k   = (const float*)d_in[7];
  const float* b_k   = (const float*)d_in[8];
  const float* W_v   = (const float*)d_in[9];
  const float* b_v   = (const float*)d_in[10];
  const float* W_o   = (const float*)d_in[11];
  const float* b_o   = (const float*)d_in[12];
  const float* W_off = (const float*)d_in[13];
  const float* b_off = (const float*)d_in[14];
  float* out = (float*)d_out;

  const size_t nelem = (size_t)LEN_IN * D_MODEL;  // 4,264,960
  unsigned short* qp    = (unsigned short*)d_ws;
  unsigned short* offsb = qp + nelem;
  unsigned short* attn  = offsb + nelem;
  unsigned* kvp = (unsigned*)(attn + nelem);
  unsigned short* Btq   = (unsigned short*)(kvp + nelem);
  unsigned short* Btk   = Btq + 256 * 256;
  unsigned short* Btv   = Btk + 256 * 256;
  unsigned short* Btoff = Btv + 256 * 256;
  unsigned short* Bto   = Btoff + 256 * 256;
  unsigned short* Btqo  = Bto + 256 * 256;
  float* bqo = (float*)(Btqo + 256 * 256);

  dim3 blk(256);
  dim3 ggrid((LEN_IN + 63) / 64, D_MODEL / 64);      // (261, 4)
  dim3 ggrid3((LEN_IN + 63) / 64, D_MODEL / 64, 3);  // q + kv + off fused

  prep_B<<<81, blk, 0, stream>>>(W_q, W_k, W_v, W_off, W_o, b_q, b_off,
                                 Btq, Btk, Btv, Btoff, Bto, bqo);
  gemm_wqo<<<dim3(4, 4), blk, 0, stream>>>(W_q, Btoff, Btqo);

  gemm_qkv<<<ggrid3, blk, 0, stream>>>(query, inp, Btq, Btk, Btv, Btqo,
                                       b_q, b_k, b_v, bqo,
                                       qp, kvp, offsb, LEN_IN);

  int n_blocks = LEN_IN * N_HEADS / 4;  // 33320
  sample_attn<<<n_blocks, blk, 0, stream>>>(qp, offsb, rp, kvp, attn);

  gemm_out<<<ggrid, blk, 0, stream>>>(attn, Bto, b_o, out, LEN_IN);
}